// Round 4
// baseline (191.031 us; speedup 1.0000x reference)
//
#include <hip/hip_runtime.h>
#include <math.h>

#define B_ 2
#define H_ 16
#define S_ 2048
#define D_ 72
#define LP 576
#define WEND 1088
#define DP 96        // padded D for qn/kn (3 chunks of 32)
#define DV 80        // padded dims for Vt (5 tiles of 16)
#define NQ (S_ - LP) // 1472 valid q rows

// attn LDS (words): P round-trip [4 waves][16 rows][40 bf16] = 1280 w (aliased);
// combine: cb [4][32][21] = 2688 w, db [4][32] = 128 w, PsD [32] = 32 w
#define CBW 2688
#define LDSW (CBW + 128 + 32)   // 2848 words = 11392 B

#define NPREP2 (B_ * H_ * S_ / 8)   // 8192 blocks, 8 rows each (2 rows/wave)
#define NVT    (32 * B_ * H_)       // 1024 blocks

typedef __bf16 bf16x8 __attribute__((ext_vector_type(8)));
typedef float f32x4 __attribute__((ext_vector_type(4)));

static __device__ __forceinline__ unsigned pack2bf(float a, float b) {
    __bf16 x = (__bf16)a, y = (__bf16)b;
    unsigned short ux = __builtin_bit_cast(unsigned short, x);
    unsigned short uy = __builtin_bit_cast(unsigned short, y);
    return (unsigned)ux | ((unsigned)uy << 16);
}

static __device__ __forceinline__ f32x4 mfma16(bf16x8 a, bf16x8 b, f32x4 c) {
    return __builtin_amdgcn_mfma_f32_16x16x32_bf16(a, b, c, 0, 0, 0);
}

// ---------- fused pre: prep (2 rows/wave, LDS-repacked uint4 stores) | vtrans (+zero) ----------
__global__ __launch_bounds__(256) void pre_kernel(
    const float* __restrict__ q, const float* __restrict__ k,
    const float* __restrict__ v,
    const float* __restrict__ pos, const float* __restrict__ pos_orig,
    const float* __restrict__ time_, const float* __restrict__ freqs,
    const float* __restrict__ t_freqs, const float* __restrict__ scale,
    unsigned* __restrict__ qn, unsigned* __restrict__ kn,
    unsigned short* __restrict__ vt, float* __restrict__ out)
{
    __shared__ __align__(16) float tile[64 * 77];  // vtrans; aliased by prep repack
    if (blockIdx.x < NPREP2) {
        unsigned short* shp = (unsigned short*)tile;  // [2][8][96] ushorts
        const int wave = threadIdx.x >> 6;
        const int lane = threadIdx.x & 63;
        const int j = lane & 31;               // lane within row
        const int rw = wave * 2 + (lane >> 5); // row within block (0..7)
        const int row = blockIdx.x * 8 + rw;
        const int s = row & (S_ - 1);
        const int h = (row >> 11) & (H_ - 1);
        const int b = row >> 15;
        const long base = (long)row * D_;
        const int p2 = (b * S_ + s) * 2;

        float oq1 = 0.f, oq2 = 0.f, ok1 = 0.f, ok2 = 0.f;
        float pq[6], pk[6];
        float ssq = 0.f, ssk = 0.f;
        if (j < 30) {
            const float x1q = q[base + j], x2q = q[base + j + 30];
            const float x1k = k[base + j], x2k = k[base + j + 30];
            const int g = j / 6, i = j - 6 * g;
            const float fh = freqs[96 + h * 6 + i];
            const float fw = freqs[h * 6 + i];
            const float ft = t_freqs[h * 6 + i];
            const float f  = (g < 2) ? fh : ((g < 4) ? fw : ft);
            const float by_o = pos_orig[p2 + 1] * 2.f - 1.f;
            const float by_p = pos[p2 + 1]      * 2.f - 1.f;
            const float bx_o = pos_orig[p2 + 0] * 2.f - 1.f;
            const float bx_p = pos[p2 + 0]      * 2.f - 1.f;
            const float bt   = time_[b * S_ + s];
            const float bv = (g == 0) ? by_o : (g == 1) ? by_p :
                             (g == 2) ? bx_o : (g == 3) ? bx_p : bt;
            float sn, cs;
            __sincosf(bv * f, &sn, &cs);
            oq1 = x1q * cs - x2q * sn;  oq2 = x2q * cs + x1q * sn;
            ok1 = x1k * cs - x2k * sn;  ok2 = x2k * cs + x1k * sn;
            ssq = oq1 * oq1 + oq2 * oq2;
            ssk = ok1 * ok1 + ok2 * ok2;
        } else {
            const int e0 = 60 + 6 * (j - 30);
            #pragma unroll
            for (int m = 0; m < 3; ++m) {
                const float2 a = *(const float2*)(q + base + e0 + 2 * m);
                const float2 c = *(const float2*)(k + base + e0 + 2 * m);
                pq[2 * m] = a.x; pq[2 * m + 1] = a.y;
                pk[2 * m] = c.x; pk[2 * m + 1] = c.y;
                ssq += a.x * a.x + a.y * a.y;
                ssk += c.x * c.x + c.y * c.y;
            }
        }
        #pragma unroll
        for (int m = 1; m < 32; m <<= 1) { ssq += __shfl_xor(ssq, m); ssk += __shfl_xor(ssk, m); }
        const float ss = sqrtf(scale[h]);
        const float fq = ss * rsqrtf(ssq + 1e-6f);
        const float fk = ss * rsqrtf(ssk + 1e-6f);

        unsigned short* sq_ = shp + rw * 96;          // [8][96] q
        unsigned short* sk_ = shp + 768 + rw * 96;    // k
        if (j < 30) {
            sq_[j]      = __builtin_bit_cast(unsigned short, (__bf16)(oq1 * fq));
            sq_[j + 30] = __builtin_bit_cast(unsigned short, (__bf16)(oq2 * fq));
            sk_[j]      = __builtin_bit_cast(unsigned short, (__bf16)(ok1 * fk));
            sk_[j + 30] = __builtin_bit_cast(unsigned short, (__bf16)(ok2 * fk));
        } else {
            const int e0 = 60 + 6 * (j - 30);
            #pragma unroll
            for (int m = 0; m < 6; ++m) {
                sq_[e0 + m] = __builtin_bit_cast(unsigned short, (__bf16)(pq[m] * fq));
                sk_[e0 + m] = __builtin_bit_cast(unsigned short, (__bf16)(pk[m] * fk));
            }
        }
        __syncthreads();
        // repack: 2 arrays x 8 rows x 12 uint4 = 192 coalesced stores
        const int t = threadIdx.x;
        if (t < 192) {
            const int arr = t / 96, rem = t - arr * 96;
            const int rr = rem / 12, seg = rem - rr * 12;
            uint4 val = make_uint4(0u, 0u, 0u, 0u);
            if (seg < 9) val = ((const uint4*)(shp + arr * 768 + rr * 96))[seg];
            unsigned* dst = (arr ? kn : qn) + ((long)(blockIdx.x * 8 + rr)) * 48;
            ((uint4*)dst)[seg] = val;
        }
    } else {
        // ---- vtrans (+ zero of out rows < LP) ----
        const int bx2 = blockIdx.x - NPREP2;
        const int st = bx2 & 31, bh = bx2 >> 5;
        const int s0 = st * 64;
        const int t = threadIdx.x;
        if (st < 9) {
            float4* o4 = (float4*)(out + (long)(bh * S_ + s0) * D_);
            for (int i = t; i < 1152; i += 256) o4[i] = make_float4(0.f, 0.f, 0.f, 0.f);
        }
        for (int i = t; i < 1152; i += 256) {
            const int r = i / 18, c = i - r * 18;
            const float4 g = ((const float4*)v)[((long)(bh * S_ + s0 + r) * 18) + c];
            float* d = &tile[r * 77 + c * 4];
            d[0] = g.x; d[1] = g.y; d[2] = g.z; d[3] = g.w;
        }
        __syncthreads();
        for (int i = t; i < 1280; i += 256) {
            const int dd = i >> 4, s4 = i & 15;
            float f0 = 0.f, f1 = 0.f, f2 = 0.f, f3 = 0.f;
            if (dd < D_) {
                f0 = tile[(s4 * 4 + 0) * 77 + dd];
                f1 = tile[(s4 * 4 + 1) * 77 + dd];
                f2 = tile[(s4 * 4 + 2) * 77 + dd];
                f3 = tile[(s4 * 4 + 3) * 77 + dd];
            }
            uint2 o; o.x = pack2bf(f0, f1); o.y = pack2bf(f2, f3);
            ((uint2*)vt)[((((long)bh * DV + dd) << 11) + s0 + s4 * 4) >> 2] = o;
        }
    }
}

// ---------- attention: 32 q-rows/block, register-pipelined K/V prefetch ----------
// Block = 32 q-rows, 4 waves. Per 128-key tile, wave w owns keys [kt*128+32w, +32).
// Tile kt+1's K/V frags are loaded while tile kt computes (register double-buffer).
// NO launch_bounds min-wave clamp: the ~170-200 reg footprint must not spill
// (round-2 lesson: the (256,3) cap forced ~1GB scratch traffic).
// Mask computed ONLY on the last tile (earlier tiles proven fully valid).
__global__ __launch_bounds__(256) void attn_kernel(
    const unsigned short* __restrict__ qn, const unsigned short* __restrict__ kn,
    const unsigned short* __restrict__ vt, float* __restrict__ out)
{
    __shared__ __align__(16) unsigned lds[LDSW];
    const int bh = blockIdx.y;
    const int q0 = LP + blockIdx.x * 32;
    const int tid = threadIdx.x;
    const int w = tid >> 6, lane = tid & 63;
    const int quad = lane >> 4, l16 = lane & 15;
    const bool causal = (q0 < WEND);
    const int ntiles = causal ? ((q0 + 159) >> 7) : 9;   // 128-key tiles

    const unsigned short* qn_b = qn + (((long)bh) << 11) * DP;
    const unsigned short* kn_b = kn + (((long)bh) << 11) * DP;
    const unsigned short* vt_b = vt + (long)bh * DV * S_;

    // Q A-frags for the 2 m-groups (rows q0+16m+l16)
    bf16x8 qf[2][3];
    #pragma unroll
    for (int m = 0; m < 2; ++m)
        #pragma unroll
        for (int c = 0; c < 3; ++c)
            qf[m][c] = *(const bf16x8*)(qn_b + (long)(q0 + 16 * m + l16) * DP + c * 32 + quad * 8);

    f32x4 o[2][5];
    float den[2][4];
    #pragma unroll
    for (int m = 0; m < 2; ++m) {
        #pragma unroll
        for (int dt = 0; dt < 5; ++dt) { o[m][dt][0]=0.f; o[m][dt][1]=0.f; o[m][dt][2]=0.f; o[m][dt][3]=0.f; }
        #pragma unroll
        for (int r = 0; r < 4; ++r) den[m][r] = 0.f;
    }

    unsigned short* Pw = (unsigned short*)lds + w * 640;  // [16 rows][40 bf16]

#define LOAD_TILE(KF, VF, KT) do {                                                           \
    const int kb_ = (KT) * 128 + 32 * w;                                                     \
    _Pragma("unroll")                                                                        \
    for (int g = 0; g < 2; ++g) {                                                            \
        _Pragma("unroll")                                                                    \
        for (int c = 0; c < 3; ++c)                                                          \
            KF[g][c] = *(const bf16x8*)(kn_b + (long)(kb_ + 16 * g + l16) * DP + c * 32 + quad * 8); \
    }                                                                                        \
    _Pragma("unroll")                                                                        \
    for (int dt = 0; dt < 5; ++dt)                                                           \
        VF[dt] = *(const bf16x8*)(vt_b + (((long)(dt * 16 + l16)) << 11) + kb_ + quad * 8);  \
} while (0)

#define COMP_TILE(KF, VF, KT) do {                                                           \
    const int kb_ = (KT) * 128 + 32 * w;                                                     \
    const bool masked_ = ((KT) == ntiles - 1);                                               \
    _Pragma("unroll")                                                                        \
    for (int m = 0; m < 2; ++m) {                                                            \
        f32x4 acc0, acc1;                                                                    \
        acc0[0]=0.f; acc0[1]=0.f; acc0[2]=0.f; acc0[3]=0.f;                                  \
        acc1[0]=0.f; acc1[1]=0.f; acc1[2]=0.f; acc1[3]=0.f;                                  \
        __builtin_amdgcn_s_setprio(1);                                                       \
        _Pragma("unroll")                                                                    \
        for (int c = 0; c < 3; ++c) {                                                        \
            acc0 = mfma16(qf[m][c], KF[0][c], acc0);                                         \
            acc1 = mfma16(qf[m][c], KF[1][c], acc1);                                         \
        }                                                                                    \
        __builtin_amdgcn_s_setprio(0);                                                       \
        _Pragma("unroll")                                                                    \
        for (int g = 0; g < 2; ++g) {                                                        \
            const int ka = kb_ + 16 * g + l16;                                               \
            _Pragma("unroll")                                                                \
            for (int r = 0; r < 4; ++r) {                                                    \
                const int qa = q0 + 16 * m + quad * 4 + r;                                   \
                float p = g ? acc1[r] : acc0[r];                                             \
                float e = __expf(p);                                                         \
                if (masked_) {                                                               \
                    const bool valid = causal ? (ka <= qa) : (ka < WEND);                    \
                    if (!valid) e = 0.f;                                                     \
                }                                                                            \
                const __bf16 pb = (__bf16)e;                                                 \
                den[m][r] += (float)pb;                                                      \
                Pw[(quad * 4 + r) * 40 + 16 * g + l16] = __builtin_bit_cast(unsigned short, pb); \
            }                                                                                \
        }                                                                                    \
        const bf16x8 pa = *(const bf16x8*)(Pw + l16 * 40 + quad * 8);                        \
        __builtin_amdgcn_s_setprio(1);                                                       \
        _Pragma("unroll")                                                                    \
        for (int dt = 0; dt < 5; ++dt)                                                       \
            o[m][dt] = mfma16(pa, VF[dt], o[m][dt]);                                         \
        __builtin_amdgcn_s_setprio(0);                                                       \
    }                                                                                        \
} while (0)

    // software-pipelined main loop: prefetch tile kt+1 while computing kt
    // (prefetch index may reach ntiles -> max key row 9*128+127 < 2048: safe)
    bf16x8 kfA[2][3], vfA[5], kfB[2][3], vfB[5];
    int kt = 0;
    LOAD_TILE(kfA, vfA, 0);
    for (;;) {
        LOAD_TILE(kfB, vfB, kt + 1);
        COMP_TILE(kfA, vfA, kt);
        if (++kt == ntiles) break;
        LOAD_TILE(kfA, vfA, kt + 1);
        COMP_TILE(kfB, vfB, kt);
        if (++kt == ntiles) break;
    }
#undef LOAD_TILE
#undef COMP_TILE

    // reduce den over key-lanes (l16) within wave
    #pragma unroll
    for (int m = 0; m < 2; ++m)
        #pragma unroll
        for (int r = 0; r < 4; ++r)
            #pragma unroll
            for (int x = 1; x < 16; x <<= 1) den[m][r] += __shfl_xor(den[m][r], x);

    // ---- cross-wave combine (keys were split across waves) ----
    __syncthreads();                       // all waves done with P region (aliased below)
    float* cb  = (float*)lds;              // [4][32][21]
    float* db  = (float*)lds + CBW;        // [4][32]
    float* PsD = (float*)lds + CBW + 128;  // [32]
    if (l16 == 0)
        #pragma unroll
        for (int m = 0; m < 2; ++m)
            #pragma unroll
            for (int r = 0; r < 4; ++r)
                db[w * 32 + 16 * m + quad * 4 + r] = den[m][r];

    // each thread owns 2 output rows: row = 8w + quad*2 + r (r=0..1), dim lane l16
    float ofin[5][2];
    #pragma unroll
    for (int dt = 0; dt < 5; ++dt) {
        __syncthreads();
        #pragma unroll
        for (int m = 0; m < 2; ++m)
            #pragma unroll
            for (int r = 0; r < 4; ++r)
                cb[w * 672 + (16 * m + quad * 4 + r) * 21 + l16] = o[m][dt][r];
        __syncthreads();
        #pragma unroll
        for (int r = 0; r < 2; ++r) {
            const int row = 8 * w + quad * 2 + r;
            ofin[dt][r] = cb[row * 21 + l16] + cb[672 + row * 21 + l16]
                        + cb[1344 + row * 21 + l16] + cb[2016 + row * 21 + l16];
        }
    }
    float dfin[2];
    #pragma unroll
    for (int r = 0; r < 2; ++r) {
        const int row = 8 * w + quad * 2 + r;
        dfin[r] = db[row] + db[32 + row] + db[64 + row] + db[96 + row];
    }

    if (!causal) {  // diagonal self-key k == q (window rows)
        // waves 0,2 compute the 16-row m-group g = w>>1 (redundant pairs avoided by gate)
        const int gq = w >> 1;
        bf16x8 qw[3];
        if (gq == 0) { qw[0] = qf[0][0]; qw[1] = qf[0][1]; qw[2] = qf[0][2]; }
        else         { qw[0] = qf[1][0]; qw[1] = qf[1][1]; qw[2] = qf[1][2]; }
        float sp = 0.f;
        #pragma unroll
        for (int c = 0; c < 3; ++c) {
            const bf16x8 kd = *(const bf16x8*)(kn_b + (long)(q0 + 16 * gq + l16) * DP + c * 32 + quad * 8);
            #pragma unroll
            for (int j = 0; j < 8; ++j) sp += (float)qw[c][j] * (float)kd[j];
        }
        sp += __shfl_xor(sp, 16);
        sp += __shfl_xor(sp, 32);
        if (quad == 0 && (w & 1) == 0) PsD[16 * gq + l16] = __expf(sp);
        __syncthreads();
        #pragma unroll
        for (int r = 0; r < 2; ++r) {
            const int row = 8 * w + quad * 2 + r;
            const float pd = PsD[row];
            dfin[r] += pd;
            const int qa = q0 + row;
            #pragma unroll
            for (int dt = 0; dt < 5; ++dt) {
                const unsigned short uv = vt_b[(((long)(dt * 16 + l16)) << 11) + qa];
                ofin[dt][r] += pd * (float)__builtin_bit_cast(__bf16, uv);
            }
        }
    }

    #pragma unroll
    for (int r = 0; r < 2; ++r) {
        const float inv = 1.f / dfin[r];
        const int qa = q0 + 8 * w + quad * 2 + r;
        float* orow = out + ((long)(bh * S_ + qa)) * D_;
        #pragma unroll
        for (int dt = 0; dt < 5; ++dt) {
            const int dim = dt * 16 + l16;
            if (dim < D_) orow[dim] = ofin[dt][r] * inv;
        }
    }
}

extern "C" void kernel_launch(void* const* d_in, const int* in_sizes, int n_in,
                              void* d_out, int out_size, void* d_ws, size_t ws_size,
                              hipStream_t stream) {
    const float* q        = (const float*)d_in[0];
    const float* k        = (const float*)d_in[1];
    const float* v        = (const float*)d_in[2];
    const float* pos      = (const float*)d_in[3];
    const float* pos_orig = (const float*)d_in[4];
    const float* time_    = (const float*)d_in[5];
    const float* freqs    = (const float*)d_in[6];
    const float* t_freqs  = (const float*)d_in[7];
    const float* scale    = (const float*)d_in[8];
    float* out = (float*)d_out;

    unsigned* qn = (unsigned*)d_ws;                                   // 12.6 MB
    unsigned* kn = qn + (size_t)B_ * H_ * S_ * 48;                    // 12.6 MB
    unsigned short* vt = (unsigned short*)(kn + (size_t)B_ * H_ * S_ * 48);  // 10.5 MB

    pre_kernel<<<dim3(NPREP2 + NVT), dim3(256), 0, stream>>>(
        q, k, v, pos, pos_orig, time_, freqs, t_freqs, scale, qn, kn, vt, out);
    attn_kernel<<<dim3(NQ / 32, B_ * H_), dim3(256), 0, stream>>>(
        (const unsigned short*)qn, (const unsigned short*)kn, vt, out);
}

// Round 6
// 187.932 us; speedup vs baseline: 1.0165x; 1.0165x over previous
//
#include <hip/hip_runtime.h>
#include <math.h>

#define B_ 2
#define H_ 16
#define S_ 2048
#define D_ 72
#define LP 576
#define WEND 1088
#define DP 96        // padded D for qn/kn (3 chunks of 32)
#define DV 80        // padded dims for Vt (5 tiles of 16)
#define NQ (S_ - LP) // 1472 valid q rows

#define NPREP2 (B_ * H_ * S_ / 8)   // 8192 blocks, 8 rows each (2 rows/wave)
#define NVT    (32 * B_ * H_)       // 1024 blocks

typedef __bf16 bf16x8 __attribute__((ext_vector_type(8)));
typedef float f32x4 __attribute__((ext_vector_type(4)));
typedef short sh4   __attribute__((ext_vector_type(4)));   // v4i16 for 16x16x16 bf16 mfma

static __device__ __forceinline__ unsigned pack2bf(float a, float b) {
    __bf16 x = (__bf16)a, y = (__bf16)b;
    unsigned short ux = __builtin_bit_cast(unsigned short, x);
    unsigned short uy = __builtin_bit_cast(unsigned short, y);
    return (unsigned)ux | ((unsigned)uy << 16);
}

static __device__ __forceinline__ f32x4 mfma32(bf16x8 a, bf16x8 b, f32x4 c) {
    return __builtin_amdgcn_mfma_f32_16x16x32_bf16(a, b, c, 0, 0, 0);
}
static __device__ __forceinline__ f32x4 mfma16k(sh4 a, sh4 b, f32x4 c) {
    return __builtin_amdgcn_mfma_f32_16x16x16bf16_1k(a, b, c, 0, 0, 0);
}
// async global->LDS, 16B per lane; dest = base + lane*16 (wave-linear)
static __device__ __forceinline__ void gll16(const void* g, void* l) {
    __builtin_amdgcn_global_load_lds((const __attribute__((address_space(1))) unsigned*)g,
                                     (__attribute__((address_space(3))) unsigned*)l, 16, 0, 0);
}

// ---------- fused pre: prep (2 rows/wave, LDS-repacked uint4 stores) | vtrans (+zero) ----------
__global__ __launch_bounds__(256) void pre_kernel(
    const float* __restrict__ q, const float* __restrict__ k,
    const float* __restrict__ v,
    const float* __restrict__ pos, const float* __restrict__ pos_orig,
    const float* __restrict__ time_, const float* __restrict__ freqs,
    const float* __restrict__ t_freqs, const float* __restrict__ scale,
    unsigned* __restrict__ qn, unsigned* __restrict__ kn,
    unsigned short* __restrict__ vt, float* __restrict__ out)
{
    __shared__ __align__(16) float tile[64 * 77];  // vtrans; aliased by prep repack
    if (blockIdx.x < NPREP2) {
        unsigned short* shp = (unsigned short*)tile;  // [2][8][96] ushorts
        const int wave = threadIdx.x >> 6;
        const int lane = threadIdx.x & 63;
        const int j = lane & 31;               // lane within row
        const int rw = wave * 2 + (lane >> 5); // row within block (0..7)
        const int row = blockIdx.x * 8 + rw;
        const int s = row & (S_ - 1);
        const int h = (row >> 11) & (H_ - 1);
        const int b = row >> 15;
        const long base = (long)row * D_;
        const int p2 = (b * S_ + s) * 2;

        float oq1 = 0.f, oq2 = 0.f, ok1 = 0.f, ok2 = 0.f;
        float pq[6], pk[6];
        float ssq = 0.f, ssk = 0.f;
        if (j < 30) {
            const float x1q = q[base + j], x2q = q[base + j + 30];
            const float x1k = k[base + j], x2k = k[base + j + 30];
            const int g = j / 6, i = j - 6 * g;
            const float fh = freqs[96 + h * 6 + i];
            const float fw = freqs[h * 6 + i];
            const float ft = t_freqs[h * 6 + i];
            const float f  = (g < 2) ? fh : ((g < 4) ? fw : ft);
            const float by_o = pos_orig[p2 + 1] * 2.f - 1.f;
            const float by_p = pos[p2 + 1]      * 2.f - 1.f;
            const float bx_o = pos_orig[p2 + 0] * 2.f - 1.f;
            const float bx_p = pos[p2 + 0]      * 2.f - 1.f;
            const float bt   = time_[b * S_ + s];
            const float bv = (g == 0) ? by_o : (g == 1) ? by_p :
                             (g == 2) ? bx_o : (g == 3) ? bx_p : bt;
            float sn, cs;
            __sincosf(bv * f, &sn, &cs);
            oq1 = x1q * cs - x2q * sn;  oq2 = x2q * cs + x1q * sn;
            ok1 = x1k * cs - x2k * sn;  ok2 = x2k * cs + x1k * sn;
            ssq = oq1 * oq1 + oq2 * oq2;
            ssk = ok1 * ok1 + ok2 * ok2;
        } else {
            const int e0 = 60 + 6 * (j - 30);
            #pragma unroll
            for (int m = 0; m < 3; ++m) {
                const float2 a = *(const float2*)(q + base + e0 + 2 * m);
                const float2 c = *(const float2*)(k + base + e0 + 2 * m);
                pq[2 * m] = a.x; pq[2 * m + 1] = a.y;
                pk[2 * m] = c.x; pk[2 * m + 1] = c.y;
                ssq += a.x * a.x + a.y * a.y;
                ssk += c.x * c.x + c.y * c.y;
            }
        }
        #pragma unroll
        for (int m = 1; m < 32; m <<= 1) { ssq += __shfl_xor(ssq, m); ssk += __shfl_xor(ssk, m); }
        const float ss = sqrtf(scale[h]);
        const float fq = ss * rsqrtf(ssq + 1e-6f);
        const float fk = ss * rsqrtf(ssk + 1e-6f);

        unsigned short* sq_ = shp + rw * 96;          // [8][96] q
        unsigned short* sk_ = shp + 768 + rw * 96;    // k
        if (j < 30) {
            sq_[j]      = __builtin_bit_cast(unsigned short, (__bf16)(oq1 * fq));
            sq_[j + 30] = __builtin_bit_cast(unsigned short, (__bf16)(oq2 * fq));
            sk_[j]      = __builtin_bit_cast(unsigned short, (__bf16)(ok1 * fk));
            sk_[j + 30] = __builtin_bit_cast(unsigned short, (__bf16)(ok2 * fk));
        } else {
            const int e0 = 60 + 6 * (j - 30);
            #pragma unroll
            for (int m = 0; m < 6; ++m) {
                sq_[e0 + m] = __builtin_bit_cast(unsigned short, (__bf16)(pq[m] * fq));
                sk_[e0 + m] = __builtin_bit_cast(unsigned short, (__bf16)(pk[m] * fk));
            }
        }
        __syncthreads();
        // repack: 2 arrays x 8 rows x 12 uint4 = 192 coalesced stores
        const int t = threadIdx.x;
        if (t < 192) {
            const int arr = t / 96, rem = t - arr * 96;
            const int rr = rem / 12, seg = rem - rr * 12;
            uint4 val = make_uint4(0u, 0u, 0u, 0u);
            if (seg < 9) val = ((const uint4*)(shp + arr * 768 + rr * 96))[seg];
            unsigned* dst = (arr ? kn : qn) + ((long)(blockIdx.x * 8 + rr)) * 48;
            ((uint4*)dst)[seg] = val;
        }
    } else {
        // ---- vtrans (+ zero of out rows < LP) ----
        const int bx2 = blockIdx.x - NPREP2;
        const int st = bx2 & 31, bh = bx2 >> 5;
        const int s0 = st * 64;
        const int t = threadIdx.x;
        if (st < 9) {
            float4* o4 = (float4*)(out + (long)(bh * S_ + s0) * D_);
            for (int i = t; i < 1152; i += 256) o4[i] = make_float4(0.f, 0.f, 0.f, 0.f);
        }
        for (int i = t; i < 1152; i += 256) {
            const int r = i / 18, c = i - r * 18;
            const float4 g = ((const float4*)v)[((long)(bh * S_ + s0 + r) * 18) + c];
            float* d = &tile[r * 77 + c * 4];
            d[0] = g.x; d[1] = g.y; d[2] = g.z; d[3] = g.w;
        }
        __syncthreads();
        for (int i = t; i < 1280; i += 256) {
            const int dd = i >> 4, s4 = i & 15;
            float f0 = 0.f, f1 = 0.f, f2 = 0.f, f3 = 0.f;
            if (dd < D_) {
                f0 = tile[(s4 * 4 + 0) * 77 + dd];
                f1 = tile[(s4 * 4 + 1) * 77 + dd];
                f2 = tile[(s4 * 4 + 2) * 77 + dd];
                f3 = tile[(s4 * 4 + 3) * 77 + dd];
            }
            uint2 o; o.x = pack2bf(f0, f1); o.y = pack2bf(f2, f3);
            ((uint2*)vt)[((((long)bh * DV + dd) << 11) + s0 + s4 * 4) >> 2] = o;
        }
    }
}

// ---------- attention: 1 wave/block, swapped-QK in-register P, async LDS pipeline ----------
// Wave owns 32 q-rows (2 m-groups of 16) and iterates ALL its keys in 32-key steps.
// Per step: 11x global_load_lds (async DMA, 16B/lane) stage K(6)/V(5) for step t+1 into
// LDS ring buffer; s_waitcnt vmcnt(11) keeps them in flight across the whole compute
// phase (compiler cannot sink async loads -> pipeline survives, unlike R4's reg version).
// Swapped QK (mfma(K,Q)) puts P at [qrow=l16][key=quad*4+r] == the exact A-frag layout
// of v_mfma_f32_16x16x16_bf16 -> P never leaves registers (no LDS round-trip, no shfl).
// Window waves (keys 0..1087 = 34 full steps) need NO masking; causal mask last step only.
__global__ __launch_bounds__(64) void attn_kernel(
    const unsigned short* __restrict__ qn, const unsigned short* __restrict__ kn,
    const unsigned short* __restrict__ vt, float* __restrict__ out)
{
    __shared__ __align__(16) unsigned stage[2][2816];   // 2 x 11 x 1KB = 22528 B

    const int bh = blockIdx.y;
    const int qw0 = LP + blockIdx.x * 32;               // this wave's 32 q-rows
    const int lane = threadIdx.x & 63;
    const int quad = lane >> 4, l16 = lane & 15;
    const bool causal = (qw0 < WEND);
    const int nt = causal ? (qw0 / 32 + 1) : (WEND / 32);   // 19..34

    const unsigned short* qn_b = qn + (((long)bh) << 11) * DP;
    const unsigned short* kn_b = kn + (((long)bh) << 11) * DP;
    const unsigned short* vt_b = vt + (long)bh * DV * S_;

    // Q B-frags: Q[col=l16 -> qrow qw0+16m+l16][k = 32c + quad*8 + j]
    bf16x8 qf[2][3];
    #pragma unroll
    for (int m = 0; m < 2; ++m)
        #pragma unroll
        for (int c = 0; c < 3; ++c)
            qf[m][c] = *(const bf16x8*)(qn_b + (long)(qw0 + 16 * m + l16) * DP + c * 32 + quad * 8);

    f32x4 o[2][5];
    float den[2] = {0.f, 0.f};
    #pragma unroll
    for (int m = 0; m < 2; ++m)
        #pragma unroll
        for (int dt = 0; dt < 5; ++dt) { o[m][dt][0]=0.f; o[m][dt][1]=0.f; o[m][dt][2]=0.f; o[m][dt][3]=0.f; }

    // staging pointers, advanced once per STAGE call (step stride: K +32*DP, V +32 keys)
    const unsigned short* pk[6];
    const unsigned short* pv[5];
    #pragma unroll
    for (int g = 0; g < 2; ++g)
        #pragma unroll
        for (int c = 0; c < 3; ++c)
            pk[g * 3 + c] = kn_b + (long)(16 * g + l16) * DP + c * 32 + quad * 8;
    #pragma unroll
    for (int dt = 0; dt < 5; ++dt)
        pv[dt] = vt_b + (((long)(dt * 16 + l16)) << 11) + quad * 8;

#define STAGE(BUF) do {                                                     \
    _Pragma("unroll")                                                       \
    for (int i_ = 0; i_ < 6; ++i_) {                                        \
        gll16(pk[i_], (void*)&(BUF)[i_ * 256]);                             \
        pk[i_] += 32 * DP;                                                  \
    }                                                                       \
    _Pragma("unroll")                                                       \
    for (int i_ = 0; i_ < 5; ++i_) {                                        \
        gll16(pv[i_], (void*)&(BUF)[(6 + i_) * 256]);                       \
        pv[i_] += 32;                                                       \
    }                                                                       \
} while (0)

    const int voffV = ((quad >> 1) * 16 + l16) * 8 + (quad & 1) * 4;  // ushort offset in V slot
    const int qa0 = qw0 + l16;   // qrow for m=0 at this lane (m=1: +16)

    STAGE(stage[0]);   // prologue: tile 0 in flight

    for (int t = 0; t < nt; ++t) {
        const unsigned short* sb = (const unsigned short*)stage[t & 1];
        // all ds_reads of the previous iteration must be complete before the DMA below
        // overwrites that buffer (write-after-read across the ring)
        asm volatile("s_waitcnt lgkmcnt(0)" ::: "memory");
        if (t + 1 < nt) {
            STAGE(stage[(t + 1) & 1]);
            asm volatile("s_waitcnt vmcnt(11)" ::: "memory");   // drain tile t; keep t+1's 11 in flight
        } else {
            asm volatile("s_waitcnt vmcnt(0)" ::: "memory");    // last tile: drain everything
        }

        // K A-frags: K[row=key 32t+16g+l16][k=32c+quad*8+j]  (identity slot: lane reads own 16B)
        bf16x8 kf[2][3];
        #pragma unroll
        for (int g = 0; g < 2; ++g)
            #pragma unroll
            for (int c = 0; c < 3; ++c)
                kf[g][c] = *(const bf16x8*)(sb + (g * 3 + c) * 512 + lane * 8);
        // V B-frags (K=16): V[key 32t+16g+quad*4+j][dim dt*16+l16]
        sh4 vf[2][5];
        #pragma unroll
        for (int g = 0; g < 2; ++g)
            #pragma unroll
            for (int dt = 0; dt < 5; ++dt)
                vf[g][dt] = *(const sh4*)(sb + 3072 + dt * 512 + g * 256 + voffV);

        const bool maskedLast = causal && (t == nt - 1);
        const int kb = t * 32;

        #pragma unroll
        for (int m = 0; m < 2; ++m) {
            f32x4 s0, s1;
            s0[0]=0.f; s0[1]=0.f; s0[2]=0.f; s0[3]=0.f;
            s1[0]=0.f; s1[1]=0.f; s1[2]=0.f; s1[3]=0.f;
            __builtin_amdgcn_s_setprio(1);
            #pragma unroll
            for (int c = 0; c < 3; ++c) {
                s0 = mfma32(kf[0][c], qf[m][c], s0);   // swapped: A=K, B=Q
                s1 = mfma32(kf[1][c], qf[m][c], s1);
            }
            __builtin_amdgcn_s_setprio(0);
            const int qa = qa0 + 16 * m;
            #pragma unroll
            for (int g = 0; g < 2; ++g) {
                const f32x4 sg = g ? s1 : s0;
                sh4 pa;
                #pragma unroll
                for (int r = 0; r < 4; ++r) {
                    float e = __expf(sg[r]);
                    if (maskedLast) {
                        const int ka = kb + 16 * g + quad * 4 + r;
                        if (ka > qa) e = 0.f;
                    }
                    const __bf16 pb = (__bf16)e;
                    den[m] += (float)pb;
                    pa[r] = __builtin_bit_cast(short, pb);
                }
                __builtin_amdgcn_s_setprio(1);
                #pragma unroll
                for (int dt = 0; dt < 5; ++dt)
                    o[m][dt] = mfma16k(pa, vf[g][dt], o[m][dt]);
                __builtin_amdgcn_s_setprio(0);
            }
        }
    }
#undef STAGE

    // diagonal self-key (window rows only): pd[m] = exp(q.k_self) per qrow=l16
    float pd[2] = {0.f, 0.f};
    if (!causal) {
        #pragma unroll
        for (int m = 0; m < 2; ++m) {
            float sp = 0.f;
            #pragma unroll
            for (int c = 0; c < 3; ++c) {
                const bf16x8 kd = *(const bf16x8*)(kn_b + (long)(qw0 + 16 * m + l16) * DP + c * 32 + quad * 8);
                #pragma unroll
                for (int j = 0; j < 8; ++j) sp += (float)qf[m][c][j] * (float)kd[j];
            }
            sp += __shfl_xor(sp, 16);
            sp += __shfl_xor(sp, 32);
            pd[m] = __expf(sp);
        }
    }

    // reduce den over quads, add diagonal
    float denf[2];
    #pragma unroll
    for (int m = 0; m < 2; ++m) {
        float d = den[m];
        d += __shfl_xor(d, 16);
        d += __shfl_xor(d, 32);
        denf[m] = causal ? d : (d + pd[m]);
    }

    // output: o[m][dt][r] = O[qw0+16m+quad*4+r][dt*16+l16]; den/pd live at qrow=l16 -> shfl
    #pragma unroll
    for (int m = 0; m < 2; ++m) {
        #pragma unroll
        for (int r = 0; r < 4; ++r) {
            const int row = 16 * m + quad * 4 + r;
            const float df = __shfl(denf[m], quad * 4 + r);
            const float inv = 1.f / df;
            const int qa = qw0 + row;
            float* orow = out + ((long)(bh * S_ + qa)) * D_;
            float pdr = 0.f;
            if (!causal) pdr = __shfl(pd[m], quad * 4 + r);
            #pragma unroll
            for (int dt = 0; dt < 5; ++dt) {
                float val = o[m][dt][r];
                if (!causal) {
                    const unsigned short uv = vt_b[(((long)(dt * 16 + l16)) << 11) + qa];
                    val += pdr * (float)__builtin_bit_cast(__bf16, uv);
                }
                const int dim = dt * 16 + l16;
                if (dim < D_) orow[dim] = val * inv;
            }
        }
    }
}

extern "C" void kernel_launch(void* const* d_in, const int* in_sizes, int n_in,
                              void* d_out, int out_size, void* d_ws, size_t ws_size,
                              hipStream_t stream) {
    const float* q        = (const float*)d_in[0];
    const float* k        = (const float*)d_in[1];
    const float* v        = (const float*)d_in[2];
    const float* pos      = (const float*)d_in[3];
    const float* pos_orig = (const float*)d_in[4];
    const float* time_    = (const float*)d_in[5];
    const float* freqs    = (const float*)d_in[6];
    const float* t_freqs  = (const float*)d_in[7];
    const float* scale    = (const float*)d_in[8];
    float* out = (float*)d_out;

    unsigned* qn = (unsigned*)d_ws;                                   // 12.6 MB
    unsigned* kn = qn + (size_t)B_ * H_ * S_ * 48;                    // 12.6 MB
    unsigned short* vt = (unsigned short*)(kn + (size_t)B_ * H_ * S_ * 48);  // 10.5 MB

    pre_kernel<<<dim3(NPREP2 + NVT), dim3(256), 0, stream>>>(
        q, k, v, pos, pos_orig, time_, freqs, t_freqs, scale, qn, kn, vt, out);
    attn_kernel<<<dim3(NQ / 32, B_ * H_), dim3(64), 0, stream>>>(
        (const unsigned short*)qn, (const unsigned short*)kn, vt, out);
}

// Round 7
// 185.953 us; speedup vs baseline: 1.0273x; 1.0106x over previous
//
#include <hip/hip_runtime.h>
#include <math.h>

#define B_ 2
#define H_ 16
#define S_ 2048
#define D_ 72
#define LP 576
#define WEND 1088
#define DP 96        // padded D for qn/kn (3 chunks of 32)
#define DV 80        // padded dims for Vt (5 tiles of 16)
#define NQ (S_ - LP) // 1472 valid q rows

#define NPREP2 (B_ * H_ * S_ / 8)   // 8192 blocks, 8 rows each (2 rows/wave)
#define NVT    (32 * B_ * H_)       // 1024 blocks

#define NQB (NQ / 32)               // 46 q-blocks per bh
#define NWG (NQB * B_ * H_)         // 1472 attn blocks
#define WPX (NWG / 8)               // 184 blocks per XCD slot

typedef __bf16 bf16x8 __attribute__((ext_vector_type(8)));
typedef float f32x4 __attribute__((ext_vector_type(4)));
typedef short sh4   __attribute__((ext_vector_type(4)));   // v4i16 for 16x16x16 bf16 mfma

static __device__ __forceinline__ unsigned pack2bf(float a, float b) {
    __bf16 x = (__bf16)a, y = (__bf16)b;
    unsigned short ux = __builtin_bit_cast(unsigned short, x);
    unsigned short uy = __builtin_bit_cast(unsigned short, y);
    return (unsigned)ux | ((unsigned)uy << 16);
}

static __device__ __forceinline__ f32x4 mfma32(bf16x8 a, bf16x8 b, f32x4 c) {
    return __builtin_amdgcn_mfma_f32_16x16x32_bf16(a, b, c, 0, 0, 0);
}
static __device__ __forceinline__ f32x4 mfma16k(sh4 a, sh4 b, f32x4 c) {
    return __builtin_amdgcn_mfma_f32_16x16x16bf16_1k(a, b, c, 0, 0, 0);
}
// async global->LDS, 16B per lane; dest = base + lane*16 (wave-linear)
static __device__ __forceinline__ void gll16(const void* g, void* l) {
    __builtin_amdgcn_global_load_lds((const __attribute__((address_space(1))) unsigned*)g,
                                     (__attribute__((address_space(3))) unsigned*)l, 16, 0, 0);
}

// ---------- fused pre: prep (2 rows/wave, LDS-repacked uint4 stores) | vtrans (+zero) ----------
__global__ __launch_bounds__(256) void pre_kernel(
    const float* __restrict__ q, const float* __restrict__ k,
    const float* __restrict__ v,
    const float* __restrict__ pos, const float* __restrict__ pos_orig,
    const float* __restrict__ time_, const float* __restrict__ freqs,
    const float* __restrict__ t_freqs, const float* __restrict__ scale,
    unsigned* __restrict__ qn, unsigned* __restrict__ kn,
    unsigned short* __restrict__ vt, float* __restrict__ out)
{
    __shared__ __align__(16) float tile[64 * 77];  // vtrans; aliased by prep repack
    if (blockIdx.x < NPREP2) {
        unsigned short* shp = (unsigned short*)tile;  // [2][8][96] ushorts
        const int wave = threadIdx.x >> 6;
        const int lane = threadIdx.x & 63;
        const int j = lane & 31;               // lane within row
        const int rw = wave * 2 + (lane >> 5); // row within block (0..7)
        const int row = blockIdx.x * 8 + rw;
        const int s = row & (S_ - 1);
        const int h = (row >> 11) & (H_ - 1);
        const int b = row >> 15;
        const long base = (long)row * D_;
        const int p2 = (b * S_ + s) * 2;

        float oq1 = 0.f, oq2 = 0.f, ok1 = 0.f, ok2 = 0.f;
        float pq[6], pk[6];
        float ssq = 0.f, ssk = 0.f;
        if (j < 30) {
            const float x1q = q[base + j], x2q = q[base + j + 30];
            const float x1k = k[base + j], x2k = k[base + j + 30];
            const int g = j / 6, i = j - 6 * g;
            const float fh = freqs[96 + h * 6 + i];
            const float fw = freqs[h * 6 + i];
            const float ft = t_freqs[h * 6 + i];
            const float f  = (g < 2) ? fh : ((g < 4) ? fw : ft);
            const float by_o = pos_orig[p2 + 1] * 2.f - 1.f;
            const float by_p = pos[p2 + 1]      * 2.f - 1.f;
            const float bx_o = pos_orig[p2 + 0] * 2.f - 1.f;
            const float bx_p = pos[p2 + 0]      * 2.f - 1.f;
            const float bt   = time_[b * S_ + s];
            const float bv = (g == 0) ? by_o : (g == 1) ? by_p :
                             (g == 2) ? bx_o : (g == 3) ? bx_p : bt;
            float sn, cs;
            __sincosf(bv * f, &sn, &cs);
            oq1 = x1q * cs - x2q * sn;  oq2 = x2q * cs + x1q * sn;
            ok1 = x1k * cs - x2k * sn;  ok2 = x2k * cs + x1k * sn;
            ssq = oq1 * oq1 + oq2 * oq2;
            ssk = ok1 * ok1 + ok2 * ok2;
        } else {
            const int e0 = 60 + 6 * (j - 30);
            #pragma unroll
            for (int m = 0; m < 3; ++m) {
                const float2 a = *(const float2*)(q + base + e0 + 2 * m);
                const float2 c = *(const float2*)(k + base + e0 + 2 * m);
                pq[2 * m] = a.x; pq[2 * m + 1] = a.y;
                pk[2 * m] = c.x; pk[2 * m + 1] = c.y;
                ssq += a.x * a.x + a.y * a.y;
                ssk += c.x * c.x + c.y * c.y;
            }
        }
        #pragma unroll
        for (int m = 1; m < 32; m <<= 1) { ssq += __shfl_xor(ssq, m); ssk += __shfl_xor(ssk, m); }
        const float ss = sqrtf(scale[h]);
        const float fq = ss * rsqrtf(ssq + 1e-6f);
        const float fk = ss * rsqrtf(ssk + 1e-6f);

        unsigned short* sq_ = shp + rw * 96;          // [8][96] q
        unsigned short* sk_ = shp + 768 + rw * 96;    // k
        if (j < 30) {
            sq_[j]      = __builtin_bit_cast(unsigned short, (__bf16)(oq1 * fq));
            sq_[j + 30] = __builtin_bit_cast(unsigned short, (__bf16)(oq2 * fq));
            sk_[j]      = __builtin_bit_cast(unsigned short, (__bf16)(ok1 * fk));
            sk_[j + 30] = __builtin_bit_cast(unsigned short, (__bf16)(ok2 * fk));
        } else {
            const int e0 = 60 + 6 * (j - 30);
            #pragma unroll
            for (int m = 0; m < 6; ++m) {
                sq_[e0 + m] = __builtin_bit_cast(unsigned short, (__bf16)(pq[m] * fq));
                sk_[e0 + m] = __builtin_bit_cast(unsigned short, (__bf16)(pk[m] * fk));
            }
        }
        __syncthreads();
        // repack: 2 arrays x 8 rows x 12 uint4 = 192 coalesced stores
        const int t = threadIdx.x;
        if (t < 192) {
            const int arr = t / 96, rem = t - arr * 96;
            const int rr = rem / 12, seg = rem - rr * 12;
            uint4 val = make_uint4(0u, 0u, 0u, 0u);
            if (seg < 9) val = ((const uint4*)(shp + arr * 768 + rr * 96))[seg];
            unsigned* dst = (arr ? kn : qn) + ((long)(blockIdx.x * 8 + rr)) * 48;
            ((uint4*)dst)[seg] = val;
        }
    } else {
        // ---- vtrans (+ zero of out rows < LP) ----
        const int bx2 = blockIdx.x - NPREP2;
        const int st = bx2 & 31, bh = bx2 >> 5;
        const int s0 = st * 64;
        const int t = threadIdx.x;
        if (st < 9) {
            float4* o4 = (float4*)(out + (long)(bh * S_ + s0) * D_);
            for (int i = t; i < 1152; i += 256) o4[i] = make_float4(0.f, 0.f, 0.f, 0.f);
        }
        for (int i = t; i < 1152; i += 256) {
            const int r = i / 18, c = i - r * 18;
            const float4 g = ((const float4*)v)[((long)(bh * S_ + s0 + r) * 18) + c];
            float* d = &tile[r * 77 + c * 4];
            d[0] = g.x; d[1] = g.y; d[2] = g.z; d[3] = g.w;
        }
        __syncthreads();
        for (int i = t; i < 1280; i += 256) {
            const int dd = i >> 4, s4 = i & 15;
            float f0 = 0.f, f1 = 0.f, f2 = 0.f, f3 = 0.f;
            if (dd < D_) {
                f0 = tile[(s4 * 4 + 0) * 77 + dd];
                f1 = tile[(s4 * 4 + 1) * 77 + dd];
                f2 = tile[(s4 * 4 + 2) * 77 + dd];
                f3 = tile[(s4 * 4 + 3) * 77 + dd];
            }
            uint2 o; o.x = pack2bf(f0, f1); o.y = pack2bf(f2, f3);
            ((uint2*)vt)[((((long)bh * DV + dd) << 11) + s0 + s4 * 4) >> 2] = o;
        }
    }
}

// ---------- attention: 1 wave/block, swapped-QK in-register P, async LDS pipeline ----------
// XCD-aware bh clustering: blocks with id%8==x (dispatched round-robin onto XCD x)
// handle only bh in [4x, 4x+4) -> per-XCD L2 working set = 4 x (kn 393KB + vt 327KB)
// = 2.9MB < 4MB L2. Without this, all 32 bh are concurrently active on every XCD
// (23MB >> L2) and the ~508MB of K/V re-reads stream from L3 at the ~7.5 TB/s wall
// that made R1/R3/R6 all land at the same 68us.
__global__ __launch_bounds__(64) void attn_kernel(
    const unsigned short* __restrict__ qn, const unsigned short* __restrict__ kn,
    const unsigned short* __restrict__ vt, float* __restrict__ out)
{
    __shared__ __align__(16) unsigned stage[2][2816];   // 2 x 11 x 1KB = 22528 B

    const int id = blockIdx.x;
    const int vlin = (id & 7) * WPX + (id >> 3);   // bijective remap (NWG % 8 == 0)
    const int bh = vlin / NQB;
    const int bx = vlin - bh * NQB;
    const int qw0 = LP + bx * 32;                  // this wave's 32 q-rows
    const int lane = threadIdx.x & 63;
    const int quad = lane >> 4, l16 = lane & 15;
    const bool causal = (qw0 < WEND);
    const int nt = causal ? (qw0 / 32 + 1) : (WEND / 32);   // 19..34

    const unsigned short* qn_b = qn + (((long)bh) << 11) * DP;
    const unsigned short* kn_b = kn + (((long)bh) << 11) * DP;
    const unsigned short* vt_b = vt + (long)bh * DV * S_;

    // Q B-frags: Q[col=l16 -> qrow qw0+16m+l16][k = 32c + quad*8 + j]
    bf16x8 qf[2][3];
    #pragma unroll
    for (int m = 0; m < 2; ++m)
        #pragma unroll
        for (int c = 0; c < 3; ++c)
            qf[m][c] = *(const bf16x8*)(qn_b + (long)(qw0 + 16 * m + l16) * DP + c * 32 + quad * 8);

    f32x4 o[2][5];
    float den[2] = {0.f, 0.f};
    #pragma unroll
    for (int m = 0; m < 2; ++m)
        #pragma unroll
        for (int dt = 0; dt < 5; ++dt) { o[m][dt][0]=0.f; o[m][dt][1]=0.f; o[m][dt][2]=0.f; o[m][dt][3]=0.f; }

    // staging pointers, advanced once per STAGE call (step stride: K +32*DP, V +32 keys)
    const unsigned short* pk[6];
    const unsigned short* pv[5];
    #pragma unroll
    for (int g = 0; g < 2; ++g)
        #pragma unroll
        for (int c = 0; c < 3; ++c)
            pk[g * 3 + c] = kn_b + (long)(16 * g + l16) * DP + c * 32 + quad * 8;
    #pragma unroll
    for (int dt = 0; dt < 5; ++dt)
        pv[dt] = vt_b + (((long)(dt * 16 + l16)) << 11) + quad * 8;

#define STAGE(BUF) do {                                                     \
    _Pragma("unroll")                                                       \
    for (int i_ = 0; i_ < 6; ++i_) {                                        \
        gll16(pk[i_], (void*)&(BUF)[i_ * 256]);                             \
        pk[i_] += 32 * DP;                                                  \
    }                                                                       \
    _Pragma("unroll")                                                       \
    for (int i_ = 0; i_ < 5; ++i_) {                                        \
        gll16(pv[i_], (void*)&(BUF)[(6 + i_) * 256]);                       \
        pv[i_] += 32;                                                       \
    }                                                                       \
} while (0)

    const int voffV = ((quad >> 1) * 16 + l16) * 8 + (quad & 1) * 4;  // ushort offset in V slot
    const int qa0 = qw0 + l16;   // qrow for m=0 at this lane (m=1: +16)

    STAGE(stage[0]);   // prologue: tile 0 in flight

    for (int t = 0; t < nt; ++t) {
        const unsigned short* sb = (const unsigned short*)stage[t & 1];
        // all ds_reads of the previous iteration must be complete before the DMA below
        // overwrites that buffer (write-after-read across the ring)
        asm volatile("s_waitcnt lgkmcnt(0)" ::: "memory");
        if (t + 1 < nt) {
            STAGE(stage[(t + 1) & 1]);
            asm volatile("s_waitcnt vmcnt(11)" ::: "memory");   // drain tile t; keep t+1's 11 in flight
        } else {
            asm volatile("s_waitcnt vmcnt(0)" ::: "memory");    // last tile: drain everything
        }

        // K A-frags: K[row=key 32t+16g+l16][k=32c+quad*8+j]  (identity slot: lane reads own 16B)
        bf16x8 kf[2][3];
        #pragma unroll
        for (int g = 0; g < 2; ++g)
            #pragma unroll
            for (int c = 0; c < 3; ++c)
                kf[g][c] = *(const bf16x8*)(sb + (g * 3 + c) * 512 + lane * 8);
        // V B-frags (K=16): V[key 32t+16g+quad*4+j][dim dt*16+l16]
        sh4 vf[2][5];
        #pragma unroll
        for (int g = 0; g < 2; ++g)
            #pragma unroll
            for (int dt = 0; dt < 5; ++dt)
                vf[g][dt] = *(const sh4*)(sb + 3072 + dt * 512 + g * 256 + voffV);

        const bool maskedLast = causal && (t == nt - 1);
        const int kb = t * 32;

        #pragma unroll
        for (int m = 0; m < 2; ++m) {
            f32x4 s0, s1;
            s0[0]=0.f; s0[1]=0.f; s0[2]=0.f; s0[3]=0.f;
            s1[0]=0.f; s1[1]=0.f; s1[2]=0.f; s1[3]=0.f;
            __builtin_amdgcn_s_setprio(1);
            #pragma unroll
            for (int c = 0; c < 3; ++c) {
                s0 = mfma32(kf[0][c], qf[m][c], s0);   // swapped: A=K, B=Q
                s1 = mfma32(kf[1][c], qf[m][c], s1);
            }
            __builtin_amdgcn_s_setprio(0);
            const int qa = qa0 + 16 * m;
            #pragma unroll
            for (int g = 0; g < 2; ++g) {
                const f32x4 sg = g ? s1 : s0;
                sh4 pa;
                #pragma unroll
                for (int r = 0; r < 4; ++r) {
                    float e = __expf(sg[r]);
                    if (maskedLast) {
                        const int ka = kb + 16 * g + quad * 4 + r;
                        if (ka > qa) e = 0.f;
                    }
                    const __bf16 pb = (__bf16)e;
                    den[m] += (float)pb;
                    pa[r] = __builtin_bit_cast(short, pb);
                }
                __builtin_amdgcn_s_setprio(1);
                #pragma unroll
                for (int dt = 0; dt < 5; ++dt)
                    o[m][dt] = mfma16k(pa, vf[g][dt], o[m][dt]);
                __builtin_amdgcn_s_setprio(0);
            }
        }
    }
#undef STAGE

    // diagonal self-key (window rows only): pd[m] = exp(q.k_self) per qrow=l16
    float pd[2] = {0.f, 0.f};
    if (!causal) {
        #pragma unroll
        for (int m = 0; m < 2; ++m) {
            float sp = 0.f;
            #pragma unroll
            for (int c = 0; c < 3; ++c) {
                const bf16x8 kd = *(const bf16x8*)(kn_b + (long)(qw0 + 16 * m + l16) * DP + c * 32 + quad * 8);
                #pragma unroll
                for (int j = 0; j < 8; ++j) sp += (float)qf[m][c][j] * (float)kd[j];
            }
            sp += __shfl_xor(sp, 16);
            sp += __shfl_xor(sp, 32);
            pd[m] = __expf(sp);
        }
    }

    // reduce den over quads, add diagonal
    float denf[2];
    #pragma unroll
    for (int m = 0; m < 2; ++m) {
        float d = den[m];
        d += __shfl_xor(d, 16);
        d += __shfl_xor(d, 32);
        denf[m] = causal ? d : (d + pd[m]);
    }

    // output: o[m][dt][r] = O[qw0+16m+quad*4+r][dt*16+l16]; den/pd live at qrow=l16 -> shfl
    #pragma unroll
    for (int m = 0; m < 2; ++m) {
        #pragma unroll
        for (int r = 0; r < 4; ++r) {
            const int row = 16 * m + quad * 4 + r;
            const float df = __shfl(denf[m], quad * 4 + r);
            const float inv = 1.f / df;
            const int qa = qw0 + row;
            float* orow = out + ((long)(bh * S_ + qa)) * D_;
            float pdr = 0.f;
            if (!causal) pdr = __shfl(pd[m], quad * 4 + r);
            #pragma unroll
            for (int dt = 0; dt < 5; ++dt) {
                float val = o[m][dt][r];
                if (!causal) {
                    const unsigned short uv = vt_b[(((long)(dt * 16 + l16)) << 11) + qa];
                    val += pdr * (float)__builtin_bit_cast(__bf16, uv);
                }
                const int dim = dt * 16 + l16;
                if (dim < D_) orow[dim] = val * inv;
            }
        }
    }
}

extern "C" void kernel_launch(void* const* d_in, const int* in_sizes, int n_in,
                              void* d_out, int out_size, void* d_ws, size_t ws_size,
                              hipStream_t stream) {
    const float* q        = (const float*)d_in[0];
    const float* k        = (const float*)d_in[1];
    const float* v        = (const float*)d_in[2];
    const float* pos      = (const float*)d_in[3];
    const float* pos_orig = (const float*)d_in[4];
    const float* time_    = (const float*)d_in[5];
    const float* freqs    = (const float*)d_in[6];
    const float* t_freqs  = (const float*)d_in[7];
    const float* scale    = (const float*)d_in[8];
    float* out = (float*)d_out;

    unsigned* qn = (unsigned*)d_ws;                                   // 12.6 MB
    unsigned* kn = qn + (size_t)B_ * H_ * S_ * 48;                    // 12.6 MB
    unsigned short* vt = (unsigned short*)(kn + (size_t)B_ * H_ * S_ * 48);  // 10.5 MB

    pre_kernel<<<dim3(NPREP2 + NVT), dim3(256), 0, stream>>>(
        q, k, v, pos, pos_orig, time_, freqs, t_freqs, scale, qn, kn, vt, out);
    attn_kernel<<<dim3(NWG), dim3(64), 0, stream>>>(
        (const unsigned short*)qn, (const unsigned short*)kn, vt, out);
}

// Round 9
// 185.350 us; speedup vs baseline: 1.0306x; 1.0033x over previous
//
#include <hip/hip_runtime.h>
#include <math.h>

#define B_ 2
#define H_ 16
#define S_ 2048
#define D_ 72
#define LP 576
#define WEND 1088
#define DP 96        // padded D for qn/kn (3 chunks of 32)
#define DV 80        // padded dims for Vt (5 tiles of 16)
#define NQ (S_ - LP) // 1472 valid q rows

#define NPREP2 (B_ * H_ * S_ / 8)   // 8192 blocks, 8 rows each (2 rows/wave)
#define NVT    (32 * B_ * H_)       // 1024 blocks

#define NQB64 (NQ / 64)             // 23 64-row q-blocks per bh
#define NWG2 (NQB64 * B_ * H_)      // 736 attn blocks (2 waves, 64 q-rows each)
#define WPX2 (NWG2 / 8)             // 92 blocks per XCD slot

typedef __bf16 bf16x8 __attribute__((ext_vector_type(8)));
typedef float f32x4 __attribute__((ext_vector_type(4)));
typedef short sh4   __attribute__((ext_vector_type(4)));   // v4i16 for 16x16x16 bf16 mfma

static __device__ __forceinline__ unsigned pack2bf(float a, float b) {
    __bf16 x = (__bf16)a, y = (__bf16)b;
    unsigned short ux = __builtin_bit_cast(unsigned short, x);
    unsigned short uy = __builtin_bit_cast(unsigned short, y);
    return (unsigned)ux | ((unsigned)uy << 16);
}

static __device__ __forceinline__ f32x4 mfma32(bf16x8 a, bf16x8 b, f32x4 c) {
    return __builtin_amdgcn_mfma_f32_16x16x32_bf16(a, b, c, 0, 0, 0);
}
static __device__ __forceinline__ f32x4 mfma16k(sh4 a, sh4 b, f32x4 c) {
    return __builtin_amdgcn_mfma_f32_16x16x16bf16_1k(a, b, c, 0, 0, 0);
}
// async global->LDS, 16B per lane; dest = base + lane*16 (wave-linear)
static __device__ __forceinline__ void gll16(const void* g, void* l) {
    __builtin_amdgcn_global_load_lds((const __attribute__((address_space(1))) unsigned*)g,
                                     (__attribute__((address_space(3))) unsigned*)l, 16, 0, 0);
}

// ---------- fused pre: prep (2 rows/wave, LDS-repacked uint4 stores) | vtrans (+zero) ----------
__global__ __launch_bounds__(256) void pre_kernel(
    const float* __restrict__ q, const float* __restrict__ k,
    const float* __restrict__ v,
    const float* __restrict__ pos, const float* __restrict__ pos_orig,
    const float* __restrict__ time_, const float* __restrict__ freqs,
    const float* __restrict__ t_freqs, const float* __restrict__ scale,
    unsigned* __restrict__ qn, unsigned* __restrict__ kn,
    unsigned short* __restrict__ vt, float* __restrict__ out)
{
    __shared__ __align__(16) float tile[64 * 77];  // vtrans; aliased by prep repack
    if (blockIdx.x < NPREP2) {
        unsigned short* shp = (unsigned short*)tile;  // [2][8][96] ushorts
        const int wave = threadIdx.x >> 6;
        const int lane = threadIdx.x & 63;
        const int j = lane & 31;               // lane within row
        const int rw = wave * 2 + (lane >> 5); // row within block (0..7)
        const int row = blockIdx.x * 8 + rw;
        const int s = row & (S_ - 1);
        const int h = (row >> 11) & (H_ - 1);
        const int b = row >> 15;
        const long base = (long)row * D_;
        const int p2 = (b * S_ + s) * 2;

        float oq1 = 0.f, oq2 = 0.f, ok1 = 0.f, ok2 = 0.f;
        float pq[6], pk[6];
        float ssq = 0.f, ssk = 0.f;
        if (j < 30) {
            const float x1q = q[base + j], x2q = q[base + j + 30];
            const float x1k = k[base + j], x2k = k[base + j + 30];
            const int g = j / 6, i = j - 6 * g;
            const float fh = freqs[96 + h * 6 + i];
            const float fw = freqs[h * 6 + i];
            const float ft = t_freqs[h * 6 + i];
            const float f  = (g < 2) ? fh : ((g < 4) ? fw : ft);
            const float by_o = pos_orig[p2 + 1] * 2.f - 1.f;
            const float by_p = pos[p2 + 1]      * 2.f - 1.f;
            const float bx_o = pos_orig[p2 + 0] * 2.f - 1.f;
            const float bx_p = pos[p2 + 0]      * 2.f - 1.f;
            const float bt   = time_[b * S_ + s];
            const float bv = (g == 0) ? by_o : (g == 1) ? by_p :
                             (g == 2) ? bx_o : (g == 3) ? bx_p : bt;
            float sn, cs;
            __sincosf(bv * f, &sn, &cs);
            oq1 = x1q * cs - x2q * sn;  oq2 = x2q * cs + x1q * sn;
            ok1 = x1k * cs - x2k * sn;  ok2 = x2k * cs + x1k * sn;
            ssq = oq1 * oq1 + oq2 * oq2;
            ssk = ok1 * ok1 + ok2 * ok2;
        } else {
            const int e0 = 60 + 6 * (j - 30);
            #pragma unroll
            for (int m = 0; m < 3; ++m) {
                const float2 a = *(const float2*)(q + base + e0 + 2 * m);
                const float2 c = *(const float2*)(k + base + e0 + 2 * m);
                pq[2 * m] = a.x; pq[2 * m + 1] = a.y;
                pk[2 * m] = c.x; pk[2 * m + 1] = c.y;
                ssq += a.x * a.x + a.y * a.y;
                ssk += c.x * c.x + c.y * c.y;
            }
        }
        #pragma unroll
        for (int m = 1; m < 32; m <<= 1) { ssq += __shfl_xor(ssq, m); ssk += __shfl_xor(ssk, m); }
        const float ss = sqrtf(scale[h]);
        // fq carries log2e so attn can use exp2 (v_exp_f32 direct, no per-score mul)
        const float fq = ss * rsqrtf(ssq + 1e-6f) * 1.44269504088896340736f;
        const float fk = ss * rsqrtf(ssk + 1e-6f);

        unsigned short* sq_ = shp + rw * 96;          // [8][96] q
        unsigned short* sk_ = shp + 768 + rw * 96;    // k
        if (j < 30) {
            sq_[j]      = __builtin_bit_cast(unsigned short, (__bf16)(oq1 * fq));
            sq_[j + 30] = __builtin_bit_cast(unsigned short, (__bf16)(oq2 * fq));
            sk_[j]      = __builtin_bit_cast(unsigned short, (__bf16)(ok1 * fk));
            sk_[j + 30] = __builtin_bit_cast(unsigned short, (__bf16)(ok2 * fk));
        } else {
            const int e0 = 60 + 6 * (j - 30);
            #pragma unroll
            for (int m = 0; m < 6; ++m) {
                sq_[e0 + m] = __builtin_bit_cast(unsigned short, (__bf16)(pq[m] * fq));
                sk_[e0 + m] = __builtin_bit_cast(unsigned short, (__bf16)(pk[m] * fk));
            }
        }
        __syncthreads();
        // repack: 2 arrays x 8 rows x 12 uint4 = 192 coalesced stores
        const int t = threadIdx.x;
        if (t < 192) {
            const int arr = t / 96, rem = t - arr * 96;
            const int rr = rem / 12, seg = rem - rr * 12;
            uint4 val = make_uint4(0u, 0u, 0u, 0u);
            if (seg < 9) val = ((const uint4*)(shp + arr * 768 + rr * 96))[seg];
            unsigned* dst = (arr ? kn : qn) + ((long)(blockIdx.x * 8 + rr)) * 48;
            ((uint4*)dst)[seg] = val;
        }
    } else {
        // ---- vtrans (+ zero of out rows < LP) ----
        const int bx2 = blockIdx.x - NPREP2;
        const int st = bx2 & 31, bh = bx2 >> 5;
        const int s0 = st * 64;
        const int t = threadIdx.x;
        if (st < 9) {
            float4* o4 = (float4*)(out + (long)(bh * S_ + s0) * D_);
            for (int i = t; i < 1152; i += 256) o4[i] = make_float4(0.f, 0.f, 0.f, 0.f);
        }
        for (int i = t; i < 1152; i += 256) {
            const int r = i / 18, c = i - r * 18;
            const float4 g = ((const float4*)v)[((long)(bh * S_ + s0 + r) * 18) + c];
            float* d = &tile[r * 77 + c * 4];
            d[0] = g.x; d[1] = g.y; d[2] = g.z; d[3] = g.w;
        }
        __syncthreads();
        for (int i = t; i < 1280; i += 256) {
            const int dd = i >> 4, s4 = i & 15;
            float f0 = 0.f, f1 = 0.f, f2 = 0.f, f3 = 0.f;
            if (dd < D_) {
                f0 = tile[(s4 * 4 + 0) * 77 + dd];
                f1 = tile[(s4 * 4 + 1) * 77 + dd];
                f2 = tile[(s4 * 4 + 2) * 77 + dd];
                f3 = tile[(s4 * 4 + 3) * 77 + dd];
            }
            uint2 o; o.x = pack2bf(f0, f1); o.y = pack2bf(f2, f3);
            ((uint2*)vt)[((((long)bh * DV + dd) << 11) + s0 + s4 * 4) >> 2] = o;
        }
    }
}

// ---------- attention: 2 waves / 64 q-rows, SHARED depth-4 K/V ring ----------
// Each wave owns 32 q-rows (qw = qw0 + 32w); both consume the SAME key stream.
// Ring = 4 slots x 11.25KB (tile j -> slot j&3). Wave w stages tiles of parity w
// TWO steps ahead; counted vmcnt(11) = "tile t landed, t+2 in flight". Per step:
// lgkmcnt(0) -> [parity wave: STAGE(t+2) + vmcnt(11)] -> s_barrier -> compute.
// vs R6/R7: DMA volume per CU halved (one stage feeds 64 rows) and prefetch slack
// doubled (2 steps) -- the two candidate mechanisms behind the 68us invariant.
// No cross-wave combine: each wave's epilogue is independent (own rows/diagonal).
__global__ __launch_bounds__(128) void attn_kernel(
    const unsigned short* __restrict__ qn, const unsigned short* __restrict__ kn,
    const unsigned short* __restrict__ vt, float* __restrict__ out)
{
    __shared__ __align__(16) unsigned stage4[4][2816];   // 4 slots x 11264B = 45KB

    const int id = blockIdx.x;
    const int vlin = (id & 7) * WPX2 + (id >> 3);   // bijective remap (NWG2 % 8 == 0)
    const int bh = vlin / NQB64;
    const int bx = vlin - bh * NQB64;
    const int qw0 = LP + bx * 64;                   // block's 64 q-rows
    const int w = threadIdx.x >> 6;                 // wave id (0/1)
    const int lane = threadIdx.x & 63;
    const int quad = lane >> 4, l16 = lane & 15;
    const int qw = qw0 + 32 * w;                    // this wave's 32 q-rows
    const bool causal = (qw0 < WEND);               // block-uniform (64 | WEND-LP)
    const int nt = causal ? (qw0 / 32 + 2) : (WEND / 32);   // 20..34 tiles

    const unsigned short* qn_b = qn + (((long)bh) << 11) * DP;
    const unsigned short* kn_b = kn + (((long)bh) << 11) * DP;
    const unsigned short* vt_b = vt + (long)bh * DV * S_;

    // Q B-frags: Q[col=l16 -> qrow qw+16m+l16][k = 32c + quad*8 + j]
    bf16x8 qf[2][3];
    #pragma unroll
    for (int m = 0; m < 2; ++m)
        #pragma unroll
        for (int c = 0; c < 3; ++c)
            qf[m][c] = *(const bf16x8*)(qn_b + (long)(qw + 16 * m + l16) * DP + c * 32 + quad * 8);

    f32x4 o[2][5];
    float den[2] = {0.f, 0.f};
    #pragma unroll
    for (int m = 0; m < 2; ++m)
        #pragma unroll
        for (int dt = 0; dt < 5; ++dt) { o[m][dt][0]=0.f; o[m][dt][1]=0.f; o[m][dt][2]=0.f; o[m][dt][3]=0.f; }

    // staging pointers (parity stream): wave w stages tiles w, w+2, ... (64-key stride)
    const unsigned short* pk[6];
    const unsigned short* pv[5];
    #pragma unroll
    for (int g = 0; g < 2; ++g)
        #pragma unroll
        for (int c = 0; c < 3; ++c)
            pk[g * 3 + c] = kn_b + (long)(32 * w + 16 * g + l16) * DP + c * 32 + quad * 8;
    #pragma unroll
    for (int dt = 0; dt < 5; ++dt)
        pv[dt] = vt_b + (((long)(dt * 16 + l16)) << 11) + 32 * w + quad * 8;

#define STAGE(BUF) do {                                                     \
    _Pragma("unroll")                                                       \
    for (int i_ = 0; i_ < 6; ++i_) {                                        \
        gll16(pk[i_], (void*)&(BUF)[i_ * 256]);                             \
        pk[i_] += 64 * DP;                                                  \
    }                                                                       \
    _Pragma("unroll")                                                       \
    for (int i_ = 0; i_ < 5; ++i_) {                                        \
        gll16(pv[i_], (void*)&(BUF)[(6 + i_) * 256]);                       \
        pv[i_] += 64;                                                       \
    }                                                                       \
} while (0)

    const int voffV = ((quad >> 1) * 16 + l16) * 8 + (quad & 1) * 4;  // ushort offset in V slot
    const int qa0 = qw + l16;   // qrow for m=0 at this lane (m=1: +16)

    STAGE(stage4[w]);   // prologue: wave w stages tile w into slot w (= w & 3)

    for (int t = 0; t < nt; ++t) {
        const unsigned short* sb = (const unsigned short*)stage4[t & 3];
        // my ds_reads of tile t-1 complete (WAR guard for slot reuse at depth 4)
        asm volatile("s_waitcnt lgkmcnt(0)" ::: "memory");
        if ((t & 1) == w) {               // my parity: confirm tile t, prefetch t+2
            if (t + 2 < nt) {
                STAGE(stage4[(t + 2) & 3]);
                asm volatile("s_waitcnt vmcnt(11)" ::: "memory");  // tile t done; t+2 in flight
            } else {
                asm volatile("s_waitcnt vmcnt(0)" ::: "memory");   // drain my last tile
            }
        }
        __builtin_amdgcn_s_barrier();     // tile t visible to both waves

        // K A-frags: K[row=key][k]  (identity slot: lane reads its own 16B)
        bf16x8 kf[2][3];
        #pragma unroll
        for (int g = 0; g < 2; ++g)
            #pragma unroll
            for (int c = 0; c < 3; ++c)
                kf[g][c] = *(const bf16x8*)(sb + (g * 3 + c) * 512 + lane * 8);
        // V B-frags (K=16): V[key 16g+quad*4+j][dim dt*16+l16]
        sh4 vf[2][5];
        #pragma unroll
        for (int g = 0; g < 2; ++g)
            #pragma unroll
            for (int dt = 0; dt < 5; ++dt)
                vf[g][dt] = *(const sh4*)(sb + 3072 + dt * 512 + g * 256 + voffV);

        const int kb = t * 32;

        #pragma unroll
        for (int m = 0; m < 2; ++m) {
            f32x4 s0, s1;
            s0[0]=0.f; s0[1]=0.f; s0[2]=0.f; s0[3]=0.f;
            s1[0]=0.f; s1[1]=0.f; s1[2]=0.f; s1[3]=0.f;
            __builtin_amdgcn_s_setprio(1);
            #pragma unroll
            for (int c = 0; c < 3; ++c) {
                s0 = mfma32(kf[0][c], qf[m][c], s0);   // swapped: A=K, B=Q
                s1 = mfma32(kf[1][c], qf[m][c], s1);
            }
            __builtin_amdgcn_s_setprio(0);
            const int qa = qa0 + 16 * m;
            #pragma unroll
            for (int g = 0; g < 2; ++g) {
                const f32x4 sg = g ? s1 : s0;
                sh4 pa;
                #pragma unroll
                for (int r = 0; r < 4; ++r) {
                    float e = exp2f(sg[r]);            // q pre-scaled by log2e
                    if (causal) {                      // mask every step (wave 0's surplus
                        const int ka = kb + 16 * g + quad * 4 + r;   // tiles fully masked)
                        if (ka > qa) e = 0.f;
                    }
                    const __bf16 pb = (__bf16)e;
                    den[m] += (float)pb;
                    pa[r] = __builtin_bit_cast(short, pb);
                }
                __builtin_amdgcn_s_setprio(1);
                #pragma unroll
                for (int dt = 0; dt < 5; ++dt)
                    o[m][dt] = mfma16k(pa, vf[g][dt], o[m][dt]);
                __builtin_amdgcn_s_setprio(0);
            }
        }
    }
#undef STAGE

    // diagonal self-key (window rows only): pd[m] = exp(q.k_self) per qrow=l16
    float pd[2] = {0.f, 0.f};
    if (!causal) {
        #pragma unroll
        for (int m = 0; m < 2; ++m) {
            float sp = 0.f;
            #pragma unroll
            for (int c = 0; c < 3; ++c) {
                const bf16x8 kd = *(const bf16x8*)(kn_b + (long)(qw + 16 * m + l16) * DP + c * 32 + quad * 8);
                #pragma unroll
                for (int j = 0; j < 8; ++j) sp += (float)qf[m][c][j] * (float)kd[j];
            }
            sp += __shfl_xor(sp, 16);
            sp += __shfl_xor(sp, 32);
            pd[m] = exp2f(sp);                        // q pre-scaled by log2e
        }
    }

    // reduce den over quads, add diagonal
    float denf[2];
    #pragma unroll
    for (int m = 0; m < 2; ++m) {
        float d = den[m];
        d += __shfl_xor(d, 16);
        d += __shfl_xor(d, 32);
        denf[m] = causal ? d : (d + pd[m]);
    }

    // output: o[m][dt][r] = O[qw+16m+quad*4+r][dt*16+l16]; den/pd live at qrow=l16 -> shfl
    #pragma unroll
    for (int m = 0; m < 2; ++m) {
        #pragma unroll
        for (int r = 0; r < 4; ++r) {
            const int row = 16 * m + quad * 4 + r;
            const float df = __shfl(denf[m], quad * 4 + r);
            const float inv = 1.f / df;
            const int qa = qw + row;
            float* orow = out + ((long)(bh * S_ + qa)) * D_;
            float pdr = 0.f;
            if (!causal) pdr = __shfl(pd[m], quad * 4 + r);
            #pragma unroll
            for (int dt = 0; dt < 5; ++dt) {
                float val = o[m][dt][r];
                if (!causal) {
                    const unsigned short uv = vt_b[(((long)(dt * 16 + l16)) << 11) + qa];
                    val += pdr * (float)__builtin_bit_cast(__bf16, uv);
                }
                const int dim = dt * 16 + l16;
                if (dim < D_) orow[dim] = val * inv;
            }
        }
    }
}

extern "C" void kernel_launch(void* const* d_in, const int* in_sizes, int n_in,
                              void* d_out, int out_size, void* d_ws, size_t ws_size,
                              hipStream_t stream) {
    const float* q        = (const float*)d_in[0];
    const float* k        = (const float*)d_in[1];
    const float* v        = (const float*)d_in[2];
    const float* pos      = (const float*)d_in[3];
    const float* pos_orig = (const float*)d_in[4];
    const float* time_    = (const float*)d_in[5];
    const float* freqs    = (const float*)d_in[6];
    const float* t_freqs  = (const float*)d_in[7];
    const float* scale    = (const float*)d_in[8];
    float* out = (float*)d_out;

    unsigned* qn = (unsigned*)d_ws;                                   // 12.6 MB
    unsigned* kn = qn + (size_t)B_ * H_ * S_ * 48;                    // 12.6 MB
    unsigned short* vt = (unsigned short*)(kn + (size_t)B_ * H_ * S_ * 48);  // 10.5 MB

    pre_kernel<<<dim3(NPREP2 + NVT), dim3(256), 0, stream>>>(
        q, k, v, pos, pos_orig, time_, freqs, t_freqs, scale, qn, kn, vt, out);
    attn_kernel<<<dim3(NWG2), dim3(128), 0, stream>>>(
        (const unsigned short*)qn, (const unsigned short*)kn, vt, out);
}